// Round 12
// baseline (163.042 us; speedup 1.0000x reference)
//
#include <hip/hip_runtime.h>
#include <stdint.h>

#define B_ROWS 16384
#define C_COLS 1000
#define D_DIM  2048

typedef __bf16 bf16x8 __attribute__((ext_vector_type(8)));
typedef float  f32x4  __attribute__((ext_vector_type(4)));
typedef unsigned short u16;

__device__ __forceinline__ u16 f2bf(float f) {
  union { float f; uint32_t u; } v; v.f = f;
  return (u16)((v.u + 0x7FFFu + ((v.u >> 16) & 1u)) >> 16);
}

// ---------------------------------------------------------------------------
// prep_w: cast W -> bf16 (XOR-swizzled per 64-elem chunk) + row norms (f32)
// ---------------------------------------------------------------------------
__global__ __launch_bounds__(256)
void prep_w(const float* __restrict__ W, u16* __restrict__ Wb,
            float* __restrict__ norms) {
  const int r = blockIdx.x;          // 0..999
  const int t = threadIdx.x;
  const float* row = W + (size_t)r * D_DIM;
  const int c = t * 8;
  float4 v0 = *reinterpret_cast<const float4*>(row + c);
  float4 v1 = *reinterpret_cast<const float4*>(row + c + 4);
  float ss = v0.x*v0.x + v0.y*v0.y + v0.z*v0.z + v0.w*v0.w
           + v1.x*v1.x + v1.y*v1.y + v1.z*v1.z + v1.w*v1.w;
  uint32_t p0 = (uint32_t)f2bf(v0.x) | ((uint32_t)f2bf(v0.y) << 16);
  uint32_t p1 = (uint32_t)f2bf(v0.z) | ((uint32_t)f2bf(v0.w) << 16);
  uint32_t p2 = (uint32_t)f2bf(v1.x) | ((uint32_t)f2bf(v1.y) << 16);
  uint32_t p3 = (uint32_t)f2bf(v1.z) | ((uint32_t)f2bf(v1.w) << 16);
  const int mask = (r & 7) << 3;
  uint4 val; val.x = p0; val.y = p1; val.z = p2; val.w = p3;
  *reinterpret_cast<uint4*>(Wb + (size_t)r * D_DIM + (c ^ mask)) = val;
  #pragma unroll
  for (int m = 32; m; m >>= 1) ss += __shfl_xor(ss, m);
  __shared__ float wss[4];
  if ((t & 63) == 0) wss[t >> 6] = ss;
  __syncthreads();
  if (t == 0) norms[r] = sqrtf(wss[0] + wss[1] + wss[2] + wss[3]);
}

// ---------------------------------------------------------------------------
// gemm8: 256x256 tile, BK=64, 8 waves, 4-phase/iter (R11 schedule).
// A: read f32 x directly — ISSUE (4x f32x4 loads) 2 phases early, WRITE
// (cvt + 2x ds_write_b128, swizzled) at the former STAGE_A slot.
// B: gload_lds from pre-swizzled bf16 Wb; counted vmcnt raised 4->6.
// FUSE=1: LDS-transpose stats epilogue + coalesced float4 logit stores.
// ---------------------------------------------------------------------------
#define ABASE(B,H) (((B)*2+(H))*8192)
#define BBASE(B,H) (32768 + ((B)*2+(H))*8192)

#define ISSUE_A(SET,H,OFF) { _Pragma("unroll") for (int j_=0;j_<2;++j_){ \
    const float* s_ = (const float*)(xa[H][j_] + (OFF)); \
    SET[2*j_]   = *reinterpret_cast<const float4*>(s_); \
    SET[2*j_+1] = *reinterpret_cast<const float4*>(s_ + 4); } }

#define WRITE_A(SET,BUF,H) { _Pragma("unroll") for (int j_=0;j_<2;++j_){ \
    bf16x8 h_; \
    h_[0]=(__bf16)SET[2*j_].x;   h_[1]=(__bf16)SET[2*j_].y; \
    h_[2]=(__bf16)SET[2*j_].z;   h_[3]=(__bf16)SET[2*j_].w; \
    h_[4]=(__bf16)SET[2*j_+1].x; h_[5]=(__bf16)SET[2*j_+1].y; \
    h_[6]=(__bf16)SET[2*j_+1].z; h_[7]=(__bf16)SET[2*j_+1].w; \
    *reinterpret_cast<bf16x8*>(wA + ((BUF)*2+(H))*16384 + j_*8192) = h_; } }

#define STAGE_B(BUF,H,OFF) { _Pragma("unroll") for (int j_=0;j_<2;++j_){ \
    u16* d_ = lds + BBASE(BUF,H) + (j_*64 + w*8)*64; \
    __builtin_amdgcn_global_load_lds( \
      (const __attribute__((address_space(1))) void*)(sb[H][j_] + (OFF)), \
      (__attribute__((address_space(3))) void*)d_, 16, 0, 0); } }

#define READ_A_KS(BUF,MH,KS) { _Pragma("unroll") for (int fr_=0;fr_<4;++fr_) \
    Acur[KS][fr_] = *reinterpret_cast<const bf16x8*>( \
        pA[KS] + ((BUF)*2+(MH))*16384 + fr_*2048); }

#define READ_B_KS(BUF,NH,DST,KS) { _Pragma("unroll") for (int fc_=0;fc_<2;++fc_) \
    DST[KS][fc_] = *reinterpret_cast<const bf16x8*>( \
        pB[KS] + ((BUF)*2+(NH))*16384 + fc_*2048); }

#define MMAK(MH,NH,BSRC,KS) { \
  _Pragma("unroll") for (int fr_=0;fr_<4;++fr_) \
    _Pragma("unroll") for (int fc_=0;fc_<2;++fc_) \
      acc[MH][fr_][NH][fc_] = __builtin_amdgcn_mfma_f32_16x16x32_bf16( \
          Acur[KS][fr_], BSRC[KS][fc_], acc[MH][fr_][NH][fc_], 0, 0, 0); }

#define BAR   __builtin_amdgcn_s_barrier()
#define LG0   asm volatile("s_waitcnt lgkmcnt(0)" ::: "memory")
#define LGK0  asm volatile("s_waitcnt lgkmcnt(0)" ::: "memory")
#define LGK4  asm volatile("s_waitcnt lgkmcnt(4)" ::: "memory")
#define LGK8  asm volatile("s_waitcnt lgkmcnt(8)" ::: "memory")
#define SCHB  __builtin_amdgcn_sched_barrier(0)
#define VM6   asm volatile("s_waitcnt vmcnt(6)" ::: "memory")
#define VM0   asm volatile("s_waitcnt vmcnt(0)" ::: "memory")
#define SETP1 __builtin_amdgcn_s_setprio(1)
#define SETP0 __builtin_amdgcn_s_setprio(0)

// online-softmax pack merge: {m,s,q,u}
#define SMERGE(m_,s_,q_,u_,om_,os_,oq_,ou_) { \
    float M_ = fmaxf(m_, om_); \
    float a_ = __expf(m_ - M_), b_ = __expf(om_ - M_); \
    float ns_ = a_*s_ + b_*os_; \
    float nq_ = a_*a_*q_ + b_*b_*oq_; \
    float nu_ = a_*(u_ + (m_-M_)*s_) + b_*(ou_ + (om_-M_)*os_); \
    m_ = M_; s_ = ns_; q_ = nq_; u_ = nu_; }

#define T2MERGE(t1_,t2_,o1_,o2_) { \
    if (o1_ > t1_) { t2_ = fmaxf(t1_, o2_); t1_ = o1_; } else t2_ = fmaxf(t2_, o1_); }

template<int FUSE>
__global__ __launch_bounds__(512, 2)
void gemm8(const float* __restrict__ x, const u16* __restrict__ Wb,
           const float* __restrict__ bias, float* __restrict__ out,
           const float* __restrict__ norms, float* __restrict__ partials) {
  __shared__ u16 lds[65536];   // 128 KiB

  const int bid = blockIdx.x;                  // 256 blocks
  const int swz = (bid & 7) * 32 + (bid >> 3); // XCD-aware, bijective
  const int tm = swz >> 2, tn = swz & 3;
  const int m0 = tm * 256, n0 = tn * 256;

  const int t = threadIdx.x, w = t >> 6, l = t & 63;
  const int wr = w >> 2, wcn = w & 3;

  f32x4 acc[2][4][2][2];
  #pragma unroll
  for (int a = 0; a < 2; ++a)
    #pragma unroll
    for (int b2 = 0; b2 < 4; ++b2)
      #pragma unroll
      for (int c2 = 0; c2 < 2; ++c2)
        #pragma unroll
        for (int d2 = 0; d2 < 2; ++d2)
          acc[a][b2][c2][d2] = (f32x4){0.f, 0.f, 0.f, 0.f};

  bf16x8 Acur[2][4], B0c[2][2], B1c[2][2];
  float4 set0[4], set1[4];

  // ---- precomputed per-lane LDS read bases (byte offsets; ra&7 == l&7) ----
  const char* ldsc = (const char*)lds;
  const int la  = l & 15;
  const int hi3 = (l >> 4) << 3;
  const int m3  = (l & 7) << 3;
  const char* pA[2];
  const char* pB[2];
  pA[0] = ldsc + wr*8192 + la*128 + (((0  + hi3) ^ m3) << 1);
  pA[1] = ldsc + wr*8192 + la*128 + (((32 + hi3) ^ m3) << 1);
  pB[0] = ldsc + 65536 + (wcn*32 + la)*128 + (((0  + hi3) ^ m3) << 1);
  pB[1] = ldsc + 65536 + (wcn*32 + la)*128 + (((32 + hi3) ^ m3) << 1);

  // ---- per-lane LDS write base for A (swizzled; r&7 == (l>>3)&7) ----
  char* wA = (char*)lds + (w*8 + (l>>3))*128
           + ((((l&7)*8) ^ (((l>>3)&7)<<3)) << 1);

  // ---- precomputed global bases: A f32 source, B bf16 source (clamped) ----
  const char* xa[2][2];
  const char* sb[2][2];
  #pragma unroll
  for (int H = 0; H < 2; ++H)
    #pragma unroll
    for (int j = 0; j < 2; ++j) {
      xa[H][j] = (const char*)x +
        (((size_t)(m0 + H*128 + j*64 + w*8 + (l>>3))) * D_DIM + (l&7)*8) * 4;
      int gr = n0 + H*128 + j*64 + w*8 + (l>>3);
      if (gr >= C_COLS) gr = C_COLS - 1;
      sb[H][j] = (const char*)Wb + ((size_t)gr * D_DIM + (l&7)*8) * 2;
    }

  // prologue: write A tile0 halves + A(1,0,k1); stage B likewise;
  // seed set0 (A-half1 @k1, for Q1's write) and set1 (A-half0 @k2, for Q2's).
  ISSUE_A(set0, 0, 0);   WRITE_A(set0, 0, 0);
  ISSUE_A(set0, 1, 0);   WRITE_A(set0, 0, 1);
  ISSUE_A(set0, 0, 256); WRITE_A(set0, 1, 0);
  STAGE_B(0,0,0); STAGE_B(0,1,0); STAGE_B(1,0,128);
  ISSUE_A(set0, 1, 256);
  ISSUE_A(set1, 0, 512);
  VM0; LG0;
  BAR;

  for (int it = 0; it < 15; ++it) {
    // Q1: write A(1,1,2it+1) [prev Q3]; reads buf0-A0; issue set0 H=1 @2it+2
    WRITE_A(set0, 1, 1);
    READ_A_KS(0,0,0); READ_B_KS(0,0,B0c,0); READ_B_KS(0,1,B1c,0);
    READ_A_KS(0,0,1); READ_B_KS(0,0,B0c,1); READ_B_KS(0,1,B1c,1);
    ISSUE_A(set0, 1, 512); STAGE_B(1,1,128);
    BAR; LGK8; SETP1; SCHB;
    MMAK(0,0,B0c,0); MMAK(0,1,B1c,0);
    LGK0; SCHB;
    MMAK(0,0,B0c,1); MMAK(0,1,B1c,1); SETP0;
    BAR;
    // Q2: write A(0,0,2it+2) [prev Q4]; reads buf0-A1; issue set1 H=0 @2it+3
    WRITE_A(set1, 0, 0);
    READ_A_KS(0,1,0); READ_A_KS(0,1,1);
    ISSUE_A(set1, 0, 768); STAGE_B(0,0,256);
    BAR; LGK4; SETP1; SCHB;
    MMAK(1,1,B1c,0); MMAK(1,0,B0c,0);
    LGK0; SCHB;
    MMAK(1,1,B1c,1); MMAK(1,0,B0c,1); SETP0;
    VM6; BAR;
    // Q3: write A(0,1,2it+2) [this Q1]; reads buf1-A0; issue set0 H=1 @2it+3
    WRITE_A(set0, 0, 1);
    READ_A_KS(1,0,0); READ_B_KS(1,0,B0c,0); READ_B_KS(1,1,B1c,0);
    READ_A_KS(1,0,1); READ_B_KS(1,0,B0c,1); READ_B_KS(1,1,B1c,1);
    ISSUE_A(set0, 1, 768); STAGE_B(0,1,256);
    BAR; LGK8; SETP1; SCHB;
    MMAK(0,0,B0c,0); MMAK(0,1,B1c,0);
    LGK0; SCHB;
    MMAK(0,0,B0c,1); MMAK(0,1,B1c,1); SETP0;
    BAR;
    // Q4: write A(1,0,2it+3) [this Q2]; reads buf1-A1; issue set1 H=0 @2it+4
    WRITE_A(set1, 1, 0);
    READ_A_KS(1,1,0); READ_A_KS(1,1,1);
    ISSUE_A(set1, 0, (it < 14) ? 1024 : 512); STAGE_B(1,0,384);
    BAR; LGK4; SETP1; SCHB;
    MMAK(1,1,B1c,0); MMAK(1,0,B0c,0);
    LGK0; SCHB;
    MMAK(1,1,B1c,1); MMAK(1,0,B0c,1); SETP0;
    VM6; BAR;
    // advance bases by 2 K-tiles
    #pragma unroll
    for (int H = 0; H < 2; ++H)
      #pragma unroll
      for (int j = 0; j < 2; ++j) { xa[H][j] += 512; sb[H][j] += 256; }
  }
  // peeled last iter (tiles 30 buf0, 31 buf1); base at KT=30
  WRITE_A(set0, 1, 1);                     // A(1,1,31), issued it=14 Q3
  READ_A_KS(0,0,0); READ_B_KS(0,0,B0c,0); READ_B_KS(0,1,B1c,0);
  READ_A_KS(0,0,1); READ_B_KS(0,0,B0c,1); READ_B_KS(0,1,B1c,1);
  STAGE_B(1,1,128);
  BAR; LGK8; SETP1; SCHB;
  MMAK(0,0,B0c,0); MMAK(0,1,B1c,0);
  LGK0; SCHB;
  MMAK(0,0,B0c,1); MMAK(0,1,B1c,1); SETP0;
  BAR;
  READ_A_KS(0,1,0); READ_A_KS(0,1,1);
  BAR; LGK4; SETP1; SCHB;
  MMAK(1,1,B1c,0); MMAK(1,0,B0c,0);
  LGK0; SCHB;
  MMAK(1,1,B1c,1); MMAK(1,0,B0c,1); SETP0;
  VM0; BAR;
  READ_A_KS(1,0,0); READ_B_KS(1,0,B0c,0); READ_B_KS(1,1,B1c,0);
  READ_A_KS(1,0,1); READ_B_KS(1,0,B0c,1); READ_B_KS(1,1,B1c,1);
  BAR; LGK8; SETP1; SCHB;
  MMAK(0,0,B0c,0); MMAK(0,1,B1c,0);
  LGK0; SCHB;
  MMAK(0,0,B0c,1); MMAK(0,1,B1c,1); SETP0;
  BAR;
  READ_A_KS(1,1,0); READ_A_KS(1,1,1);
  BAR; LGK4; SETP1; SCHB;
  MMAK(1,1,B1c,0); MMAK(1,0,B0c,0);
  LGK0; SCHB;
  MMAK(1,1,B1c,1); MMAK(1,0,B0c,1); SETP0;

  // ---- epilogue: per-thread col metadata
  float bv[2][2]; bool okc[2][2];
  #pragma unroll
  for (int nh = 0; nh < 2; ++nh)
    #pragma unroll
    for (int fc = 0; fc < 2; ++fc) {
      int col = n0 + nh*128 + wcn*32 + fc*16 + (l & 15);
      okc[nh][fc] = (col < C_COLS);
      bv[nh][fc]  = okc[nh][fc] ? bias[col] : 0.f;
    }

  if constexpr (!FUSE) {
    #pragma unroll
    for (int mh = 0; mh < 2; ++mh)
      #pragma unroll
      for (int nh = 0; nh < 2; ++nh)
        #pragma unroll
        for (int fc = 0; fc < 2; ++fc)
          if (okc[nh][fc]) {
            int col = n0 + nh*128 + wcn*32 + fc*16 + (l & 15);
            #pragma unroll
            for (int fr = 0; fr < 4; ++fr) {
              int row0 = m0 + mh*128 + wr*64 + fr*16 + ((l >> 4) << 2);
              #pragma unroll
              for (int j = 0; j < 4; ++j)
                out[(size_t)(row0 + j) * C_COLS + col] = acc[mh][fr][nh][fc][j] + bv[nh][fc];
            }
          }
  }

  if constexpr (FUSE) {
    // LDS-transpose: sf = [128][256] f32, swizzle col ^= (row&7)<<2.
    float* sf = (float*)lds;
    const int rrow = t >> 2;
    const int q    = t & 3;
    BAR;
    #pragma unroll
    for (int mh = 0; mh < 2; ++mh) {
      #pragma unroll
      for (int fr = 0; fr < 4; ++fr)
        #pragma unroll
        for (int j = 0; j < 4; ++j) {
          int rl = wr*64 + fr*16 + ((l >> 4) << 2) + j;
          int sw = (rl & 7) << 2;
          #pragma unroll
          for (int nh = 0; nh < 2; ++nh)
            #pragma unroll
            for (int fc = 0; fc < 2; ++fc) {
              int c = nh*128 + wcn*32 + fc*16 + (l & 15);
              sf[rl*256 + (c ^ sw)] = acc[mh][fr][nh][fc][j] + bv[nh][fc];
            }
        }
      LG0; BAR;
      // pass 1: coalesced logit store + max + top2(raw) + top2(normalized)
      float m=-3.4e38f, t1=-3.4e38f, t2=-3.4e38f, n1=-3.4e38f, n2=-3.4e38f;
      #pragma unroll
      for (int i = 0; i < 16; ++i) {
        int U = i*4 + q;
        f32x4 v4 = *reinterpret_cast<const f32x4*>(
            &sf[rrow*256 + 4*(U ^ (rrow & 7))]);
        f32x4 w4 = *reinterpret_cast<const f32x4*>(&norms[n0 + 4*U]);
        if (n0 + 4*U + 3 < C_COLS)
          *reinterpret_cast<f32x4*>(
              &out[(size_t)(m0 + mh*128 + rrow) * C_COLS + n0 + 4*U]) = v4;
        #pragma unroll
        for (int e = 0; e < 4; ++e) {
          int col = n0 + 4*U + e;
          if (col < C_COLS) {
            float v = v4[e];
            m = fmaxf(m, v);
            if (v > t1) { t2 = t1; t1 = v; } else if (v > t2) t2 = v;
            float nv = v / (w4[e] + 1e-8f);
            if (nv > n1) { n2 = n1; n1 = nv; } else if (nv > n2) n2 = nv;
          }
        }
      }
      // pass 2: exp sums vs per-thread max
      float s = 0.f, qq = 0.f, u = 0.f;
      #pragma unroll
      for (int i = 0; i < 16; ++i) {
        int U = i*4 + q;
        f32x4 v4 = *reinterpret_cast<const f32x4*>(
            &sf[rrow*256 + 4*(U ^ (rrow & 7))]);
        #pragma unroll
        for (int e = 0; e < 4; ++e) {
          int col = n0 + 4*U + e;
          if (col < C_COLS) {
            float d = v4[e] - m;
            float ee = __expf(d);
            s += ee; qq += ee*ee; u += d*ee;
          }
        }
      }
      LG0;
      #pragma unroll
      for (int msk = 1; msk < 4; msk <<= 1) {
        float o1 = __shfl_xor(t1, msk), o2 = __shfl_xor(t2, msk);
        T2MERGE(t1, t2, o1, o2);
        float p1 = __shfl_xor(n1, msk), p2 = __shfl_xor(n2, msk);
        T2MERGE(n1, n2, p1, p2);
        float om = __shfl_xor(m, msk), os = __shfl_xor(s, msk);
        float oq = __shfl_xor(qq, msk), ou = __shfl_xor(u, msk);
        SMERGE(m, s, qq, u, om, os, oq, ou);
      }
      if (q == 0) {
        float* pp = partials + ((size_t)(m0 + mh*128 + rrow) * 4 + tn) * 8;
        float4 lo; lo.x=t1; lo.y=t2; lo.z=n1; lo.w=n2;
        float4 hi; hi.x=m;  hi.y=s;  hi.z=qq; hi.w=u;
        *reinterpret_cast<float4*>(pp)     = lo;
        *reinterpret_cast<float4*>(pp + 4) = hi;
      }
      if (mh == 0) { BAR; }
    }
  }
}

// ---------------------------------------------------------------------------
// selector2: merge 4 N-tile packs per row -> selection score
// ---------------------------------------------------------------------------
__global__ __launch_bounds__(256)
void selector2(const float* __restrict__ partials,
               const float* __restrict__ selw, const float* __restrict__ selt,
               const float* __restrict__ ethr, float* __restrict__ out2) {
  const int row = blockIdx.x * 256 + threadIdx.x;
  const float* pp = partials + (size_t)row * 32;
  float P[4][8];
  #pragma unroll
  for (int wv = 0; wv < 4; ++wv) {
    float4 lo = *reinterpret_cast<const float4*>(pp + wv*8);
    float4 hi = *reinterpret_cast<const float4*>(pp + wv*8 + 4);
    P[wv][0]=lo.x; P[wv][1]=lo.y; P[wv][2]=lo.z; P[wv][3]=lo.w;
    P[wv][4]=hi.x; P[wv][5]=hi.y; P[wv][6]=hi.z; P[wv][7]=hi.w;
  }
  float t1=P[0][0], t2=P[0][1], n1=P[0][2], n2=P[0][3];
  float m=P[0][4], s=P[0][5], q=P[0][6], u=P[0][7];
  #pragma unroll
  for (int wv = 1; wv < 4; ++wv) {
    T2MERGE(t1, t2, P[wv][0], P[wv][1]);
    T2MERGE(n1, n2, P[wv][2], P[wv][3]);
    SMERGE(m, s, q, u, P[wv][4], P[wv][5], P[wv][6], P[wv][7]);
  }
  float sc0 = 1.f / s;
  float sc1 = 1.f - (s * s) / q;
  float sc2 = u / s - __logf(s);
  float sc3 = n1 - n2;
  float sc4 = t1 - t2;
  float ens = selw[0] * tanhf(sc0 - selt[0])
            + selw[1] * tanhf(sc1 - selt[1])
            + selw[2] * tanhf(sc2 - selt[2])
            + selw[3] * tanhf(sc3 - selt[3])
            + selw[4] * tanhf(sc4 - selt[4]);
  out2[row] = tanhf(ens - ethr[0]);
}

// ---------------------------------------------------------------------------
// selector (fallback, reads logits): per-row stats -> score
// ---------------------------------------------------------------------------
__global__ __launch_bounds__(256)
void selector(const float* __restrict__ logits, const float* __restrict__ norms,
              const float* __restrict__ selw, const float* __restrict__ selt,
              const float* __restrict__ ethr, float* __restrict__ out) {
  __shared__ float nrm[1024];
  const int t = threadIdx.x;
  #pragma unroll
  for (int i = 0; i < 4; ++i) {
    int idx = t + i * 256;
    nrm[idx] = (idx < C_COLS) ? norms[idx] : 1.0f;
  }
  __syncthreads();
  const int w = t >> 6, l = t & 63;
  const int row = blockIdx.x * 4 + w;
  const float* lp = logits + (size_t)row * C_COLS;
  float lg[16];
  float t1 = -3.4e38f, t2 = -3.4e38f, n1 = -3.4e38f, n2 = -3.4e38f;
  #pragma unroll
  for (int i = 0; i < 4; ++i) {
    float4 v4 = *reinterpret_cast<const float4*>(lp + l * 4 + i * 256);
    #pragma unroll
    for (int j = 0; j < 4; ++j) {
      int idx = l * 4 + i * 256 + j;
      float raw = (j == 0) ? v4.x : (j == 1) ? v4.y : (j == 2) ? v4.z : v4.w;
      bool ok = (idx < C_COLS);
      float v = ok ? raw : -3.4e38f;
      lg[i * 4 + j] = v;
      if (v > t1) { t2 = t1; t1 = v; } else if (v > t2) t2 = v;
      float nv = ok ? raw / (nrm[idx] + 1e-8f) : -3.4e38f;
      if (nv > n1) { n2 = n1; n1 = nv; } else if (nv > n2) n2 = nv;
    }
  }
  #pragma unroll
  for (int m = 1; m < 64; m <<= 1) {
    float o1 = __shfl_xor(t1, m), o2 = __shfl_xor(t2, m);
    T2MERGE(t1, t2, o1, o2);
    float p1 = __shfl_xor(n1, m), p2 = __shfl_xor(n2, m);
    T2MERGE(n1, n2, p1, p2);
  }
  const float mx = t1;
  float S = 0.f, sq = 0.f;
  float ex[16];
  #pragma unroll
  for (int i = 0; i < 16; ++i) {
    float e = (lg[i] > -1e38f) ? __expf(lg[i] - mx) : 0.f;
    ex[i] = e; S += e; sq += e * e;
  }
  #pragma unroll
  for (int m = 1; m < 64; m <<= 1) { S += __shfl_xor(S, m); sq += __shfl_xor(sq, m); }
  float ent = 0.f;
  #pragma unroll
  for (int i = 0; i < 16; ++i)
    if (lg[i] > -1e38f) { float p = ex[i] / S; ent += p * __logf(p + 1e-10f); }
  #pragma unroll
  for (int m = 1; m < 64; m <<= 1) ent += __shfl_xor(ent, m);
  if (l == 0) {
    float ens = selw[0] * tanhf(1.f / S - selt[0])
              + selw[1] * tanhf(1.f - (S * S) / sq - selt[1])
              + selw[2] * tanhf(ent - selt[2])
              + selw[3] * tanhf(n1 - n2 - selt[3])
              + selw[4] * tanhf(t1 - t2 - selt[4]);
    out[row] = tanhf(ens - ethr[0]);
  }
}

// ---------------------------------------------------------------------------
extern "C" void kernel_launch(void* const* d_in, const int* in_sizes, int n_in,
                              void* d_out, int out_size, void* d_ws, size_t ws_size,
                              hipStream_t stream) {
  const float* x    = (const float*)d_in[0];
  const float* W    = (const float*)d_in[1];
  const float* b    = (const float*)d_in[2];
  const float* selw = (const float*)d_in[3];
  const float* selt = (const float*)d_in[4];
  const float* ethr = (const float*)d_in[5];
  float* out = (float*)d_out;
  float* out2 = out + (size_t)B_ROWS * C_COLS;

  u16*   Wb    = (u16*)d_ws;                         // 4,096,000 B
  float* norms = (float*)((char*)d_ws + 4096000);    // 4,000 B (pad to 4,100,096)
  float* parts = (float*)((char*)d_ws + 4100096);    // 2,097,152 B

  const size_t need_fuse = 4100096 + 2097152;

  prep_w<<<C_COLS, 256, 0, stream>>>(W, Wb, norms);
  if (ws_size >= need_fuse) {
    gemm8<1><<<256, 512, 0, stream>>>(x, Wb, b, out, norms, parts);
    selector2<<<B_ROWS / 256, 256, 0, stream>>>(parts, selw, selt, ethr, out2);
  } else {
    gemm8<0><<<256, 512, 0, stream>>>(x, Wb, b, out, norms, nullptr);
    selector<<<B_ROWS / 4, 256, 0, stream>>>(out, norms, selw, selt, ethr, out2);
  }
}

// Round 13
// 117.124 us; speedup vs baseline: 1.3920x; 1.3920x over previous
//
#include <hip/hip_runtime.h>
#include <stdint.h>

#define B_ROWS 16384
#define C_COLS 1000
#define D_DIM  2048

typedef __bf16 bf16x8 __attribute__((ext_vector_type(8)));
typedef float  f32x4  __attribute__((ext_vector_type(4)));
typedef unsigned short u16;

__device__ __forceinline__ u16 f2bf(float f) {
  union { float f; uint32_t u; } v; v.f = f;
  return (u16)((v.u + 0x7FFFu + ((v.u >> 16) & 1u)) >> 16);
}

// ---------------------------------------------------------------------------
// prep: blocks 0..999 cast W row -> Wb (swizzled) + norms; blocks 1000..17383
// cast x row (r-1000) -> xb (swizzled). Swizzle: elem c -> c ^ ((row&7)<<3).
// ---------------------------------------------------------------------------
__global__ __launch_bounds__(256)
void prep(const float* __restrict__ W, const float* __restrict__ x,
          u16* __restrict__ Wb, u16* __restrict__ xb, float* __restrict__ norms) {
  const int r = blockIdx.x;
  const int t = threadIdx.x;
  const bool isW = (r < C_COLS);
  const float* src = isW ? (W + (size_t)r * D_DIM)
                         : (x + (size_t)(r - C_COLS) * D_DIM);
  u16* dst = isW ? (Wb + (size_t)r * D_DIM)
                 : (xb + (size_t)(r - C_COLS) * D_DIM);
  const int c = t * 8;
  float4 v0 = *reinterpret_cast<const float4*>(src + c);
  float4 v1 = *reinterpret_cast<const float4*>(src + c + 4);
  uint32_t p0 = (uint32_t)f2bf(v0.x) | ((uint32_t)f2bf(v0.y) << 16);
  uint32_t p1 = (uint32_t)f2bf(v0.z) | ((uint32_t)f2bf(v0.w) << 16);
  uint32_t p2 = (uint32_t)f2bf(v1.x) | ((uint32_t)f2bf(v1.y) << 16);
  uint32_t p3 = (uint32_t)f2bf(v1.z) | ((uint32_t)f2bf(v1.w) << 16);
  const int row_id = isW ? r : (r - C_COLS);
  const int m2 = (row_id & 7) << 3;
  uint4 val; val.x = p0; val.y = p1; val.z = p2; val.w = p3;
  *reinterpret_cast<uint4*>(dst + (c ^ m2)) = val;
  if (isW) {
    float ss = v0.x*v0.x + v0.y*v0.y + v0.z*v0.z + v0.w*v0.w
             + v1.x*v1.x + v1.y*v1.y + v1.z*v1.z + v1.w*v1.w;
    #pragma unroll
    for (int m = 32; m; m >>= 1) ss += __shfl_xor(ss, m);
    __shared__ float wss[4];
    if ((t & 63) == 0) wss[t >> 6] = ss;
    __syncthreads();
    if (t == 0) norms[r] = sqrtf(wss[0] + wss[1] + wss[2] + wss[3]);
  }
}

// ---------------------------------------------------------------------------
// gemm8: 256x256 tile, BK=64, 8 waves, 4-phase/iter schedule with ks-split
// MFMA + counted lgkmcnt so ks1 ds_reads drain under ks0 MFMAs.
// Stage addressing: precomputed pointers + C-level byte delta, offset arg 0.
// FUSE=1: stats epilogue also emits the logit stores (coalesced float4).
// ---------------------------------------------------------------------------
#define ABASE(B,H) (((B)*2+(H))*8192)
#define BBASE(B,H) (32768 + ((B)*2+(H))*8192)

#define STAGE_A(BUF,H,OFF) { _Pragma("unroll") for (int j_=0;j_<2;++j_){ \
    u16* d_ = lds + ABASE(BUF,H) + (j_*64 + w*8)*64; \
    __builtin_amdgcn_global_load_lds( \
      (const __attribute__((address_space(1))) void*)(sa[H][j_] + (OFF)), \
      (__attribute__((address_space(3))) void*)d_, 16, 0, 0); } }

#define STAGE_B(BUF,H,OFF) { _Pragma("unroll") for (int j_=0;j_<2;++j_){ \
    u16* d_ = lds + BBASE(BUF,H) + (j_*64 + w*8)*64; \
    __builtin_amdgcn_global_load_lds( \
      (const __attribute__((address_space(1))) void*)(sb[H][j_] + (OFF)), \
      (__attribute__((address_space(3))) void*)d_, 16, 0, 0); } }

#define READ_A_KS(BUF,MH,KS) { _Pragma("unroll") for (int fr_=0;fr_<4;++fr_) \
    Acur[KS][fr_] = *reinterpret_cast<const bf16x8*>( \
        pA[KS] + ((BUF)*2+(MH))*16384 + fr_*2048); }

#define READ_B_KS(BUF,NH,DST,KS) { _Pragma("unroll") for (int fc_=0;fc_<2;++fc_) \
    DST[KS][fc_] = *reinterpret_cast<const bf16x8*>( \
        pB[KS] + ((BUF)*2+(NH))*16384 + fc_*2048); }

#define MMAK(MH,NH,BSRC,KS) { \
  _Pragma("unroll") for (int fr_=0;fr_<4;++fr_) \
    _Pragma("unroll") for (int fc_=0;fc_<2;++fc_) \
      acc[MH][fr_][NH][fc_] = __builtin_amdgcn_mfma_f32_16x16x32_bf16( \
          Acur[KS][fr_], BSRC[KS][fc_], acc[MH][fr_][NH][fc_], 0, 0, 0); }

#define BAR   __builtin_amdgcn_s_barrier()
#define LG0   asm volatile("s_waitcnt lgkmcnt(0)" ::: "memory")
#define LGK0  asm volatile("s_waitcnt lgkmcnt(0)" ::: "memory")
#define LGK4  asm volatile("s_waitcnt lgkmcnt(4)" ::: "memory")
#define LGK8  asm volatile("s_waitcnt lgkmcnt(8)" ::: "memory")
#define SCHB  __builtin_amdgcn_sched_barrier(0)
#define VM4   asm volatile("s_waitcnt vmcnt(4)" ::: "memory")
#define VM0   asm volatile("s_waitcnt vmcnt(0)" ::: "memory")
#define SETP1 __builtin_amdgcn_s_setprio(1)
#define SETP0 __builtin_amdgcn_s_setprio(0)

// online-softmax pack merge: {m,s,q,u}
#define SMERGE(m_,s_,q_,u_,om_,os_,oq_,ou_) { \
    float M_ = fmaxf(m_, om_); \
    float a_ = __expf(m_ - M_), b_ = __expf(om_ - M_); \
    float ns_ = a_*s_ + b_*os_; \
    float nq_ = a_*a_*q_ + b_*b_*oq_; \
    float nu_ = a_*(u_ + (m_-M_)*s_) + b_*(ou_ + (om_-M_)*os_); \
    m_ = M_; s_ = ns_; q_ = nq_; u_ = nu_; }

#define T2MERGE(t1_,t2_,o1_,o2_) { \
    if (o1_ > t1_) { t2_ = fmaxf(t1_, o2_); t1_ = o1_; } else t2_ = fmaxf(t2_, o1_); }

template<int FUSE>
__global__ __launch_bounds__(512, 2)
void gemm8(const u16* __restrict__ xb, const u16* __restrict__ Wb,
           const float* __restrict__ bias, float* __restrict__ out,
           const float* __restrict__ norms, float* __restrict__ partials) {
  __shared__ u16 lds[65536];   // 128 KiB

  const int bid = blockIdx.x;                  // 256 blocks
  const int swz = (bid & 7) * 32 + (bid >> 3); // XCD-aware, bijective
  const int tm = swz >> 2, tn = swz & 3;
  const int m0 = tm * 256, n0 = tn * 256;

  const int t = threadIdx.x, w = t >> 6, l = t & 63;
  const int wr = w >> 2, wcn = w & 3;

  f32x4 acc[2][4][2][2];
  #pragma unroll
  for (int a = 0; a < 2; ++a)
    #pragma unroll
    for (int b2 = 0; b2 < 4; ++b2)
      #pragma unroll
      for (int c2 = 0; c2 < 2; ++c2)
        #pragma unroll
        for (int d2 = 0; d2 < 2; ++d2)
          acc[a][b2][c2][d2] = (f32x4){0.f, 0.f, 0.f, 0.f};

  bf16x8 Acur[2][4], B0c[2][2], B1c[2][2];

  // ---- precomputed per-lane LDS read bases (byte offsets; ra&7 == l&7) ----
  const char* ldsc = (const char*)lds;
  const int la  = l & 15;
  const int hi3 = (l >> 4) << 3;
  const int m3  = (l & 7) << 3;
  const char* pA[2];
  const char* pB[2];
  pA[0] = ldsc + wr*8192 + la*128 + (((0  + hi3) ^ m3) << 1);
  pA[1] = ldsc + wr*8192 + la*128 + (((32 + hi3) ^ m3) << 1);
  pB[0] = ldsc + 65536 + (wcn*32 + la)*128 + (((0  + hi3) ^ m3) << 1);
  pB[1] = ldsc + 65536 + (wcn*32 + la)*128 + (((32 + hi3) ^ m3) << 1);

  // ---- precomputed global stage bases (KT=0; B clamp hoisted) ----
  const char* sa[2][2];
  const char* sb[2][2];
  #pragma unroll
  for (int H = 0; H < 2; ++H)
    #pragma unroll
    for (int j = 0; j < 2; ++j) {
      sa[H][j] = (const char*)xb +
        (((size_t)(m0 + H*128 + j*64 + w*8 + (l>>3))) * D_DIM + (l&7)*8) * 2;
      int gr = n0 + H*128 + j*64 + w*8 + (l>>3);
      if (gr >= C_COLS) gr = C_COLS - 1;
      sb[H][j] = (const char*)Wb + ((size_t)gr * D_DIM + (l&7)*8) * 2;
    }

  // prologue: tile0 all 4 halves (buf0) + tile1 half0 (buf1)
  STAGE_A(0,0,0); STAGE_B(0,0,0); STAGE_A(0,1,0); STAGE_B(0,1,0);
  STAGE_A(1,0,128); STAGE_B(1,0,128);
  VM4;           // tile0 landed; A(1,0),B(1,0) remain outstanding
  BAR;

  for (int it = 0; it < 15; ++it) {
    // Q1: A0 x {B0,B1}, buf0 (16 reads, ks0-first)
    READ_A_KS(0,0,0); READ_B_KS(0,0,B0c,0); READ_B_KS(0,1,B1c,0);
    READ_A_KS(0,0,1); READ_B_KS(0,0,B0c,1); READ_B_KS(0,1,B1c,1);
    STAGE_A(1,1,128); STAGE_B(1,1,128);
    BAR; LGK8; SETP1; SCHB;
    MMAK(0,0,B0c,0); MMAK(0,1,B1c,0);
    LGK0; SCHB;
    MMAK(0,0,B0c,1); MMAK(0,1,B1c,1); SETP0;
    BAR;
    // Q2: A1 x {B1,B0}, buf0 (8 reads)
    READ_A_KS(0,1,0); READ_A_KS(0,1,1);
    STAGE_A(0,0,256); STAGE_B(0,0,256);
    BAR; LGK4; SETP1; SCHB;
    MMAK(1,1,B1c,0); MMAK(1,0,B0c,0);
    LGK0; SCHB;
    MMAK(1,1,B1c,1); MMAK(1,0,B0c,1); SETP0;
    VM4; BAR;
    // Q3: A0 x {B0,B1}, buf1
    READ_A_KS(1,0,0); READ_B_KS(1,0,B0c,0); READ_B_KS(1,1,B1c,0);
    READ_A_KS(1,0,1); READ_B_KS(1,0,B0c,1); READ_B_KS(1,1,B1c,1);
    STAGE_A(0,1,256); STAGE_B(0,1,256);
    BAR; LGK8; SETP1; SCHB;
    MMAK(0,0,B0c,0); MMAK(0,1,B1c,0);
    LGK0; SCHB;
    MMAK(0,0,B0c,1); MMAK(0,1,B1c,1); SETP0;
    BAR;
    // Q4: A1 x {B1,B0}, buf1
    READ_A_KS(1,1,0); READ_A_KS(1,1,1);
    STAGE_A(1,0,384); STAGE_B(1,0,384);
    BAR; LGK4; SETP1; SCHB;
    MMAK(1,1,B1c,0); MMAK(1,0,B0c,0);
    LGK0; SCHB;
    MMAK(1,1,B1c,1); MMAK(1,0,B0c,1); SETP0;
    VM4; BAR;
    // advance stage bases by 2 K-tiles (256 B)
    #pragma unroll
    for (int H = 0; H < 2; ++H)
      #pragma unroll
      for (int j = 0; j < 2; ++j) { sa[H][j] += 256; sb[H][j] += 256; }
  }
  // peeled last iter (tiles 30 buf0, 31 buf1); bases at KT=30
  READ_A_KS(0,0,0); READ_B_KS(0,0,B0c,0); READ_B_KS(0,1,B1c,0);
  READ_A_KS(0,0,1); READ_B_KS(0,0,B0c,1); READ_B_KS(0,1,B1c,1);
  STAGE_A(1,1,128); STAGE_B(1,1,128);
  BAR; LGK8; SETP1; SCHB;
  MMAK(0,0,B0c,0); MMAK(0,1,B1c,0);
  LGK0; SCHB;
  MMAK(0,0,B0c,1); MMAK(0,1,B1c,1); SETP0;
  BAR;
  READ_A_KS(0,1,0); READ_A_KS(0,1,1);
  BAR; LGK4; SETP1; SCHB;
  MMAK(1,1,B1c,0); MMAK(1,0,B0c,0);
  LGK0; SCHB;
  MMAK(1,1,B1c,1); MMAK(1,0,B0c,1); SETP0;
  VM0; BAR;
  READ_A_KS(1,0,0); READ_B_KS(1,0,B0c,0); READ_B_KS(1,1,B1c,0);
  READ_A_KS(1,0,1); READ_B_KS(1,0,B0c,1); READ_B_KS(1,1,B1c,1);
  BAR; LGK8; SETP1; SCHB;
  MMAK(0,0,B0c,0); MMAK(0,1,B1c,0);
  LGK0; SCHB;
  MMAK(0,0,B0c,1); MMAK(0,1,B1c,1); SETP0;
  BAR;
  READ_A_KS(1,1,0); READ_A_KS(1,1,1);
  BAR; LGK4; SETP1; SCHB;
  MMAK(1,1,B1c,0); MMAK(1,0,B0c,0);
  LGK0; SCHB;
  MMAK(1,1,B1c,1); MMAK(1,0,B0c,1); SETP0;

  // ---- epilogue: per-thread col metadata
  float bv[2][2]; bool okc[2][2];
  #pragma unroll
  for (int nh = 0; nh < 2; ++nh)
    #pragma unroll
    for (int fc = 0; fc < 2; ++fc) {
      int col = n0 + nh*128 + wcn*32 + fc*16 + (l & 15);
      okc[nh][fc] = (col < C_COLS);
      bv[nh][fc]  = okc[nh][fc] ? bias[col] : 0.f;
    }

  if constexpr (!FUSE) {
    // store logits (non-fused path only)
    #pragma unroll
    for (int mh = 0; mh < 2; ++mh)
      #pragma unroll
      for (int nh = 0; nh < 2; ++nh)
        #pragma unroll
        for (int fc = 0; fc < 2; ++fc)
          if (okc[nh][fc]) {
            int col = n0 + nh*128 + wcn*32 + fc*16 + (l & 15);
            #pragma unroll
            for (int fr = 0; fr < 4; ++fr) {
              int row0 = m0 + mh*128 + wr*64 + fr*16 + ((l >> 4) << 2);
              #pragma unroll
              for (int j = 0; j < 4; ++j)
                out[(size_t)(row0 + j) * C_COLS + col] = acc[mh][fr][nh][fc][j] + bv[nh][fc];
            }
          }
  }

  if constexpr (FUSE) {
    // LDS-transpose: sf = [128][256] f32, swizzle col ^= (row&7)<<2.
    // Pass 1 reads back logical float4s -> coalesced global store + stats.
    float* sf = (float*)lds;
    const int rrow = t >> 2;           // reader row 0..127
    const int q    = t & 3;            // reader lane-in-group
    BAR;                               // main-loop LDS use complete
    #pragma unroll
    for (int mh = 0; mh < 2; ++mh) {
      #pragma unroll
      for (int fr = 0; fr < 4; ++fr)
        #pragma unroll
        for (int j = 0; j < 4; ++j) {
          int rl = wr*64 + fr*16 + ((l >> 4) << 2) + j;     // 0..127
          int sw = (rl & 7) << 2;
          #pragma unroll
          for (int nh = 0; nh < 2; ++nh)
            #pragma unroll
            for (int fc = 0; fc < 2; ++fc) {
              int c = nh*128 + wcn*32 + fc*16 + (l & 15);
              sf[rl*256 + (c ^ sw)] = acc[mh][fr][nh][fc][j] + bv[nh][fc];
            }
        }
      LG0; BAR;
      // pass 1: logit store (float4, 64B-contiguous per 4-lane group)
      //          + row max + top2(raw) + top2(normalized)
      float m=-3.4e38f, t1=-3.4e38f, t2=-3.4e38f, n1=-3.4e38f, n2=-3.4e38f;
      #pragma unroll
      for (int i = 0; i < 16; ++i) {
        int U = i*4 + q;
        f32x4 v4 = *reinterpret_cast<const f32x4*>(
            &sf[rrow*256 + 4*(U ^ (rrow & 7))]);
        f32x4 w4 = *reinterpret_cast<const f32x4*>(&norms[n0 + 4*U]);
        if (n0 + 4*U + 3 < C_COLS)
          *reinterpret_cast<f32x4*>(
              &out[(size_t)(m0 + mh*128 + rrow) * C_COLS + n0 + 4*U]) = v4;
        #pragma unroll
        for (int e = 0; e < 4; ++e) {
          int col = n0 + 4*U + e;
          if (col < C_COLS) {
            float v = v4[e];
            m = fmaxf(m, v);
            if (v > t1) { t2 = t1; t1 = v; } else if (v > t2) t2 = v;
            float nv = v / (w4[e] + 1e-8f);
            if (nv > n1) { n2 = n1; n1 = nv; } else if (nv > n2) n2 = nv;
          }
        }
      }
      // pass 2: exp sums vs per-thread max
      float s = 0.f, qq = 0.f, u = 0.f;
      #pragma unroll
      for (int i = 0; i < 16; ++i) {
        int U = i*4 + q;
        f32x4 v4 = *reinterpret_cast<const f32x4*>(
            &sf[rrow*256 + 4*(U ^ (rrow & 7))]);
        #pragma unroll
        for (int e = 0; e < 4; ++e) {
          int col = n0 + 4*U + e;
          if (col < C_COLS) {
            float d = v4[e] - m;
            float ee = __expf(d);
            s += ee; qq += ee*ee; u += d*ee;
          }
        }
      }
      LG0;
      // merge 4 consecutive lanes (same row)
      #pragma unroll
      for (int msk = 1; msk < 4; msk <<= 1) {
        float o1 = __shfl_xor(t1, msk), o2 = __shfl_xor(t2, msk);
        T2MERGE(t1, t2, o1, o2);
        float p1 = __shfl_xor(n1, msk), p2 = __shfl_xor(n2, msk);
        T2MERGE(n1, n2, p1, p2);
        float om = __shfl_xor(m, msk), os = __shfl_xor(s, msk);
        float oq = __shfl_xor(qq, msk), ou = __shfl_xor(u, msk);
        SMERGE(m, s, qq, u, om, os, oq, ou);
      }
      if (q == 0) {
        float* pp = partials + ((size_t)(m0 + mh*128 + rrow) * 4 + tn) * 8;
        float4 lo; lo.x=t1; lo.y=t2; lo.z=n1; lo.w=n2;
        float4 hi; hi.x=m;  hi.y=s;  hi.z=qq; hi.w=u;
        *reinterpret_cast<float4*>(pp)     = lo;
        *reinterpret_cast<float4*>(pp + 4) = hi;
      }
      if (mh == 0) { BAR; }            // readers done before next scatter
    }
  }
}

// ---------------------------------------------------------------------------
// selector2: merge 4 N-tile packs per row -> selection score
// ---------------------------------------------------------------------------
__global__ __launch_bounds__(256)
void selector2(const float* __restrict__ partials,
               const float* __restrict__ selw, const float* __restrict__ selt,
               const float* __restrict__ ethr, float* __restrict__ out2) {
  const int row = blockIdx.x * 256 + threadIdx.x;
  const float* pp = partials + (size_t)row * 32;
  float P[4][8];
  #pragma unroll
  for (int wv = 0; wv < 4; ++wv) {
    float4 lo = *reinterpret_cast<const float4*>(pp + wv*8);
    float4 hi = *reinterpret_cast<const float4*>(pp + wv*8 + 4);
    P[wv][0]=lo.x; P[wv][1]=lo.y; P[wv][2]=lo.z; P[wv][3]=lo.w;
    P[wv][4]=hi.x; P[wv][5]=hi.y; P[wv][6]=hi.z; P[wv][7]=hi.w;
  }
  float t1=P[0][0], t2=P[0][1], n1=P[0][2], n2=P[0][3];
  float m=P[0][4], s=P[0][5], q=P[0][6], u=P[0][7];
  #pragma unroll
  for (int wv = 1; wv < 4; ++wv) {
    T2MERGE(t1, t2, P[wv][0], P[wv][1]);
    T2MERGE(n1, n2, P[wv][2], P[wv][3]);
    SMERGE(m, s, q, u, P[wv][4], P[wv][5], P[wv][6], P[wv][7]);
  }
  float sc0 = 1.f / s;                 // SRMax
  float sc1 = 1.f - (s * s) / q;       // SRDoctor
  float sc2 = u / s - __logf(s);       // SREntropy (neg-entropy)
  float sc3 = n1 - n2;                 // RLGeoM
  float sc4 = t1 - t2;                 // RLConfM
  float ens = selw[0] * tanhf(sc0 - selt[0])
            + selw[1] * tanhf(sc1 - selt[1])
            + selw[2] * tanhf(sc2 - selt[2])
            + selw[3] * tanhf(sc3 - selt[3])
            + selw[4] * tanhf(sc4 - selt[4]);
  out2[row] = tanhf(ens - ethr[0]);
}

// ---------------------------------------------------------------------------
// selector (fallback, reads logits): per-row stats -> score
// ---------------------------------------------------------------------------
__global__ __launch_bounds__(256)
void selector(const float* __restrict__ logits, const float* __restrict__ norms,
              const float* __restrict__ selw, const float* __restrict__ selt,
              const float* __restrict__ ethr, float* __restrict__ out) {
  __shared__ float nrm[1024];
  const int t = threadIdx.x;
  #pragma unroll
  for (int i = 0; i < 4; ++i) {
    int idx = t + i * 256;
    nrm[idx] = (idx < C_COLS) ? norms[idx] : 1.0f;
  }
  __syncthreads();
  const int w = t >> 6, l = t & 63;
  const int row = blockIdx.x * 4 + w;
  const float* lp = logits + (size_t)row * C_COLS;
  float lg[16];
  float t1 = -3.4e38f, t2 = -3.4e38f, n1 = -3.4e38f, n2 = -3.4e38f;
  #pragma unroll
  for (int i = 0; i < 4; ++i) {
    float4 v4 = *reinterpret_cast<const float4*>(lp + l * 4 + i * 256);
    #pragma unroll
    for (int j = 0; j < 4; ++j) {
      int idx = l * 4 + i * 256 + j;
      float raw = (j == 0) ? v4.x : (j == 1) ? v4.y : (j == 2) ? v4.z : v4.w;
      bool ok = (idx < C_COLS);
      float v = ok ? raw : -3.4e38f;
      lg[i * 4 + j] = v;
      if (v > t1) { t2 = t1; t1 = v; } else if (v > t2) t2 = v;
      float nv = ok ? raw / (nrm[idx] + 1e-8f) : -3.4e38f;
      if (nv > n1) { n2 = n1; n1 = nv; } else if (nv > n2) n2 = nv;
    }
  }
  #pragma unroll
  for (int m = 1; m < 64; m <<= 1) {
    float o1 = __shfl_xor(t1, m), o2 = __shfl_xor(t2, m);
    T2MERGE(t1, t2, o1, o2);
    float p1 = __shfl_xor(n1, m), p2 = __shfl_xor(n2, m);
    T2MERGE(n1, n2, p1, p2);
  }
  const float mx = t1;
  float S = 0.f, sq = 0.f;
  float ex[16];
  #pragma unroll
  for (int i = 0; i < 16; ++i) {
    float e = (lg[i] > -1e38f) ? __expf(lg[i] - mx) : 0.f;
    ex[i] = e; S += e; sq += e * e;
  }
  #pragma unroll
  for (int m = 1; m < 64; m <<= 1) { S += __shfl_xor(S, m); sq += __shfl_xor(sq, m); }
  float ent = 0.f;
  #pragma unroll
  for (int i = 0; i < 16; ++i)
    if (lg[i] > -1e38f) { float p = ex[i] / S; ent += p * __logf(p + 1e-10f); }
  #pragma unroll
  for (int m = 1; m < 64; m <<= 1) ent += __shfl_xor(ent, m);
  if (l == 0) {
    float ens = selw[0] * tanhf(1.f / S - selt[0])
              + selw[1] * tanhf(1.f - (S * S) / sq - selt[1])
              + selw[2] * tanhf(ent - selt[2])
              + selw[3] * tanhf(n1 - n2 - selt[3])
              + selw[4] * tanhf(t1 - t2 - selt[4]);
    out[row] = tanhf(ens - ethr[0]);
  }
}

// ---------------------------------------------------------------------------
extern "C" void kernel_launch(void* const* d_in, const int* in_sizes, int n_in,
                              void* d_out, int out_size, void* d_ws, size_t ws_size,
                              hipStream_t stream) {
  const float* x    = (const float*)d_in[0];
  const float* W    = (const float*)d_in[1];
  const float* b    = (const float*)d_in[2];
  const float* selw = (const float*)d_in[3];
  const float* selt = (const float*)d_in[4];
  const float* ethr = (const float*)d_in[5];
  float* out = (float*)d_out;
  float* out2 = out + (size_t)B_ROWS * C_COLS;

  u16*   Wb    = (u16*)d_ws;                         // 4,096,000 B
  float* norms = (float*)((char*)d_ws + 4096000);    // 4,000 B (pad to 4,100,096)
  u16*   xb    = (u16*)((char*)d_ws + 4100096);      // 67,108,864 B
  float* parts = (float*)((char*)d_ws + 4100096 + 67108864);  // 2,097,152 B

  const size_t need_fuse = 4100096 + 67108864 + 2097152;
  const size_t need_r4   = 4100096 + 67108864;

  if (ws_size >= need_fuse) {
    prep<<<C_COLS + B_ROWS, 256, 0, stream>>>(W, x, Wb, xb, norms);
    gemm8<1><<<256, 512, 0, stream>>>(xb, Wb, b, out, norms, parts);
    selector2<<<B_ROWS / 256, 256, 0, stream>>>(parts, selw, selt, ethr, out2);
  } else if (ws_size >= need_r4) {
    prep<<<C_COLS + B_ROWS, 256, 0, stream>>>(W, x, Wb, xb, norms);
    gemm8<0><<<256, 512, 0, stream>>>(xb, Wb, b, out, norms, nullptr);
    selector<<<B_ROWS / 4, 256, 0, stream>>>(out, norms, selw, selt, ethr, out2);
  }
}